// Round 4
// baseline (299.233 us; speedup 1.0000x reference)
//
#include <hip/hip_runtime.h>
#include <math.h>

// Problem constants (B=2, N=512, C=64, H=8)
constexpr int NDIM  = 512;
constexpr int CDIM  = 64;
constexpr int HDIM  = 8;
constexpr int CHUNK = 32;              // rows per K1 block
constexpr int NCHNK = NDIM / CHUNK;    // 16 chunks per (b,m)

// ---------------- K1: projection + exp + mask + partial sums ----------------
// Block = (bm, chunk). 256 threads. Lane t: c4 = t&15 (float4 within 64-c row),
// sub = t>>4 (row subgroup). Pass p handles row rr = p*16 + sub.
// Global loads: float4 index == t  -> lane-contiguous 1 KiB per wave (coalesced).
// Dot reduced over the 16-lane group via shfl_xor(1,2,4,8).
__global__ __launch_bounds__(256, 4)
void k1_proj(const float* __restrict__ q,
             const float* __restrict__ kk,
             const float* __restrict__ mask,
             const float* __restrict__ W,      // (H, 2C)
             const float* __restrict__ bias,   // (H,)
             float* __restrict__ out,          // unnormalized exp vals
             float* __restrict__ ws_partial)   // (1024, 16, 8) chunk sums
{
    __shared__ float lds_val[CHUNK * 9];   // padded stride 9 (bank-spread)
    __shared__ float red[4 * HDIM];

    const int blk = blockIdx.x;
    const int bm  = blk >> 4;          // 0..1023
    const int ch  = blk & 15;          // 0..15
    const int t   = threadIdx.x;
    const int c4  = t & 15;
    const int sub = t >> 4;

    // Per-lane W fragment: for each head, the 4 q-coeffs and 4 k-coeffs
    // matching this lane's c-chunk. 64 VGPRs, loaded once (L1/L2-hot).
    const float4* W4 = (const float4*)W;           // one W row = 32 float4
    float4 wq[HDIM], wk[HDIM];
#pragma unroll
    for (int h = 0; h < HDIM; ++h) {
        wq[h] = W4[h * 32 + c4];
        wk[h] = W4[h * 32 + 16 + c4];
    }
    float bz[HDIM];
#pragma unroll
    for (int h = 0; h < HDIM; ++h) bz[h] = bias[h];   // uniform -> s_load

    const size_t rowbase = ((size_t)bm * NDIM + (size_t)ch * CHUNK);
    const float4* qbase = (const float4*)(q  + rowbase * CDIM);
    const float4* kbase = (const float4*)(kk + rowbase * CDIM);

    float psum[HDIM];
#pragma unroll
    for (int h = 0; h < HDIM; ++h) psum[h] = 0.0f;

#pragma unroll
    for (int pass = 0; pass < 2; ++pass) {
        const int rr = pass * 16 + sub;
        // coalesced: float4 index = rr*16 + c4 = pass*256 + t
        const float4 xq = qbase[pass * 256 + t];
        const float4 xk = kbase[pass * 256 + t];
        const float mval = mask[bm * NDIM + ch * CHUNK + rr];

#pragma unroll
        for (int h = 0; h < HDIM; ++h) {
            float a = xq.x * wq[h].x + xq.y * wq[h].y
                    + xq.z * wq[h].z + xq.w * wq[h].w
                    + xk.x * wk[h].x + xk.y * wk[h].y
                    + xk.z * wk[h].z + xk.w * wk[h].w;
            // reduce over the 16 lanes sharing this row
            a += __shfl_xor(a, 1, 64);
            a += __shfl_xor(a, 2, 64);
            a += __shfl_xor(a, 4, 64);
            a += __shfl_xor(a, 8, 64);
            float v = __expf(a + bz[h]) * mval;   // replicated on 16 lanes
            psum[h] += v;
            if (c4 == 0) lds_val[rr * 9 + h] = v;
        }
    }

    // wave-level: sum across the 4 subgroups only (xor 16, 32) -> no overcount
#pragma unroll
    for (int h = 0; h < HDIM; ++h) {
        float s = psum[h];
        s += __shfl_xor(s, 16, 64);
        s += __shfl_xor(s, 32, 64);
        psum[h] = s;
    }
    if ((t & 63) == 0) {
        const int w = t >> 6;
#pragma unroll
        for (int h = 0; h < HDIM; ++h) red[w * HDIM + h] = psum[h];
    }
    __syncthreads();

    if (t < HDIM) {
        float s = red[t] + red[HDIM + t] + red[2 * HDIM + t] + red[3 * HDIM + t];
        ws_partial[(size_t)(bm * NCHNK + ch) * HDIM + t] = s;
    }

    // write the 32x8 unnormalized slab, coalesced float4
    if (t < 64) {
        const int row = t >> 1;
        const int hb  = (t & 1) * 4;
        float4 o;
        o.x = lds_val[row * 9 + hb + 0];
        o.y = lds_val[row * 9 + hb + 1];
        o.z = lds_val[row * 9 + hb + 2];
        o.w = lds_val[row * 9 + hb + 3];
        ((float4*)(out + rowbase * HDIM))[t] = o;
    }
}

// ---------------- K2: reduce chunk sums, normalize ----------------
__global__ __launch_bounds__(256, 4)
void k2_norm(const float* __restrict__ ws_partial,
             float* __restrict__ out)
{
    __shared__ float part[NCHNK * HDIM];   // 128
    __shared__ float rsum[HDIM];

    const int bm = blockIdx.x;
    const int t  = threadIdx.x;

    if (t < NCHNK * HDIM)
        part[t] = ws_partial[(size_t)bm * NCHNK * HDIM + t];
    __syncthreads();
    if (t < HDIM) {
        float s = 0.0f;
#pragma unroll
        for (int c = 0; c < NCHNK; ++c) s += part[c * HDIM + t];
        rsum[t] = 1.0f / s;
    }
    __syncthreads();

    float4 rs0 = make_float4(rsum[0], rsum[1], rsum[2], rsum[3]);
    float4 rs1 = make_float4(rsum[4], rsum[5], rsum[6], rsum[7]);

    float4* o4 = (float4*)(out + (size_t)bm * NDIM * HDIM);  // 1024 float4
#pragma unroll
    for (int i = 0; i < 4; ++i) {
        const int idx = i * 256 + t;
        float4 v = o4[idx];
        const float4 sc = (idx & 1) ? rs1 : rs0;   // float offset idx*4 -> h group
        v.x *= sc.x; v.y *= sc.y; v.z *= sc.z; v.w *= sc.w;
        o4[idx] = v;
    }
}

extern "C" void kernel_launch(void* const* d_in, const int* in_sizes, int n_in,
                              void* d_out, int out_size, void* d_ws, size_t ws_size,
                              hipStream_t stream) {
    const float* q    = (const float*)d_in[0];
    const float* k    = (const float*)d_in[1];
    const float* mask = (const float*)d_in[2];
    const float* W    = (const float*)d_in[3];
    const float* b    = (const float*)d_in[4];
    float* out = (float*)d_out;
    float* ws_partial = (float*)d_ws;   // 1024*16*8 floats = 512 KB

    hipLaunchKernelGGL(k1_proj, dim3(2 * NDIM * NCHNK), dim3(256), 0, stream,
                       q, k, mask, W, b, out, ws_partial);
    hipLaunchKernelGGL(k2_norm, dim3(2 * NDIM), dim3(256), 0, stream,
                       ws_partial, out);
}